// Round 1
// baseline (528.259 us; speedup 1.0000x reference)
//
#include <hip/hip_runtime.h>

#define BATCH 16
#define NN 512   // n  (j index, "nxt" side; rows of X)
#define MM 512   // m  (i index, "cur" side; cols of X)
#define DD 128
#define QP_ITERS 20

// ---------------------------------------------------------------------------
// row_norms: rc[b*512+p] = ||nc[b,p]||^2 + ||ec[b,p]||^2
//            rn[b*512+p] = ||nn[b,p]||^2 + ||en[b,p]||^2
// one 64-thread block per (b,p); float2 loads.
// ---------------------------------------------------------------------------
__global__ __launch_bounds__(64) void row_norms_kernel(
    const float* __restrict__ nc, const float* __restrict__ ec,
    const float* __restrict__ nn, const float* __restrict__ en,
    float* __restrict__ rc, float* __restrict__ rn)
{
    int row = blockIdx.x;            // b*512 + p
    int t   = threadIdx.x;           // 0..63
    size_t base = (size_t)row * DD;

    float2 a = ((const float2*)(nc + base))[t];
    float2 b = ((const float2*)(ec + base))[t];
    float vc = a.x*a.x + a.y*a.y + b.x*b.x + b.y*b.y;

    float2 c = ((const float2*)(nn + base))[t];
    float2 d = ((const float2*)(en + base))[t];
    float vn = c.x*c.x + c.y*c.y + d.x*d.x + d.y*d.y;

    #pragma unroll
    for (int off = 32; off; off >>= 1) {
        vc += __shfl_down(vc, off);
        vn += __shfl_down(vn, off);
    }
    if (t == 0) { rc[row] = vc; rn[row] = vn; }
}

// ---------------------------------------------------------------------------
// gemm_q: qm[b,j,i] = 0.5*(rc[b,i]+rn[b,j]) - (nc_i . nn_j + ec_i . en_j)
// 64x64 tile per 256-thread block, 4x4 micro-tile, K staged through LDS.
// Also atomically accumulates sum(qm) and sum(qm^2) per batch.
// ---------------------------------------------------------------------------
__global__ __launch_bounds__(256) void gemm_q_kernel(
    const float* __restrict__ nc, const float* __restrict__ ec,
    const float* __restrict__ nn, const float* __restrict__ en,
    const float* __restrict__ rc, const float* __restrict__ rn,
    float* __restrict__ qm, float* __restrict__ sumq, float* __restrict__ sumq2)
{
    int b  = blockIdx.z;
    int it = blockIdx.x;   // i tile (cur), 64 wide
    int jt = blockIdx.y;   // j tile (nxt), 64 wide
    int tid = threadIdx.x;
    int tx = tid & 15, ty = tid >> 4;

    __shared__ float As[64][17];   // nxt rows (j) x k-chunk
    __shared__ float Bs[64][17];   // cur rows (i) x k-chunk

    float acc[4][4] = {};

    const float* a0 = nn + ((size_t)b*NN + jt*64) * DD;
    const float* a1 = en + ((size_t)b*NN + jt*64) * DD;
    const float* b0 = nc + ((size_t)b*MM + it*64) * DD;
    const float* b1 = ec + ((size_t)b*MM + it*64) * DD;

    int lrow = tid >> 4;   // 0..15
    int lk   = tid & 15;   // 0..15

    for (int mat = 0; mat < 2; ++mat) {
        const float* ap = mat ? a1 : a0;
        const float* bp = mat ? b1 : b0;
        for (int kc = 0; kc < DD; kc += 16) {
            __syncthreads();
            #pragma unroll
            for (int r = 0; r < 4; ++r) {
                int row = lrow + r*16;
                As[row][lk] = ap[(size_t)row*DD + kc + lk];
                Bs[row][lk] = bp[(size_t)row*DD + kc + lk];
            }
            __syncthreads();
            #pragma unroll
            for (int k = 0; k < 16; ++k) {
                float ar[4], br[4];
                #pragma unroll
                for (int r = 0; r < 4; ++r) ar[r] = As[ty*4 + r][k];
                #pragma unroll
                for (int c = 0; c < 4; ++c) br[c] = Bs[tx*4 + c][k];
                #pragma unroll
                for (int r = 0; r < 4; ++r)
                    #pragma unroll
                    for (int c = 0; c < 4; ++c)
                        acc[r][c] += ar[r] * br[c];
            }
        }
    }

    float qs = 0.f, q2s = 0.f;
    #pragma unroll
    for (int r = 0; r < 4; ++r) {
        int j = jt*64 + ty*4 + r;
        float rnj = rn[b*NN + j];
        float4 o;
        float v;
        int i0 = it*64 + tx*4;
        v = 0.5f*(rc[b*MM + i0 + 0] + rnj) - acc[r][0]; o.x = v; qs += v; q2s += v*v;
        v = 0.5f*(rc[b*MM + i0 + 1] + rnj) - acc[r][1]; o.y = v; qs += v; q2s += v*v;
        v = 0.5f*(rc[b*MM + i0 + 2] + rnj) - acc[r][2]; o.z = v; qs += v; q2s += v*v;
        v = 0.5f*(rc[b*MM + i0 + 3] + rnj) - acc[r][3]; o.w = v; qs += v; q2s += v*v;
        *(float4*)(qm + ((size_t)b*NN + j)*MM + i0) = o;
    }

    // block reduce qs/q2s -> 2 atomics per block
    #pragma unroll
    for (int off = 32; off; off >>= 1) {
        qs  += __shfl_down(qs,  off);
        q2s += __shfl_down(q2s, off);
    }
    __shared__ float red[8];
    int wid = tid >> 6, lane = tid & 63;
    if (lane == 0) { red[wid] = qs; red[4 + wid] = q2s; }
    __syncthreads();
    if (tid == 0) {
        atomicAdd(&sumq[b],  red[0] + red[1] + red[2] + red[3]);
        atomicAdd(&sumq2[b], red[4] + red[5] + red[6] + red[7]);
    }
}

// ---------------------------------------------------------------------------
// scalar helpers
// ---------------------------------------------------------------------------
__global__ void zero_scalars_kernel(float* __restrict__ sumq, float* __restrict__ sumq2,
                                    float* __restrict__ sbuf)
{
    int t = threadIdx.x;
    if (t < BATCH) { sumq[t] = 0.f; sumq2[t] = 0.f; }
    for (int k = t; k < (QP_ITERS + 2) * BATCH; k += blockDim.x) sbuf[k] = 0.f;
}

__global__ void init_scalars_kernel(const float* __restrict__ sumq,
                                    const float* __restrict__ sumq2,
                                    float* __restrict__ lrbuf, float* __restrict__ sbuf)
{
    int b = threadIdx.x;
    if (b < BATCH) {
        lrbuf[b] = 0.5f / (sumq2[b] + 1e-8f);
        sbuf[1 * BATCH + b] = sumq[b] * (1.0f / (float)MM);   // s1 = sum(qm)/m
    }
}

// ---------------------------------------------------------------------------
// K1 (row phase): per (b,j) row of X:
//   X = Xprev * f   (lazy column scale from previous iteration)
//   V = clip(X - c*qm, 0, 1),  c = 2*lr[b]*s_t[b]
//   Xout = V / (rowsum(V) + 1e-8)
// one 128-thread block per row; float4 element access.
// ---------------------------------------------------------------------------
template <bool FIRST>
__global__ __launch_bounds__(128) void k1_row_kernel(
    const float* __restrict__ qm, const float* __restrict__ Xin,
    const float* __restrict__ f, const float* __restrict__ lrbuf,
    const float* __restrict__ s_t, float* __restrict__ Xout)
{
    int blk = blockIdx.x;           // b*NN + j
    int b   = blk >> 9;
    int tid = threadIdx.x;          // 0..127
    size_t base = (size_t)blk * MM;

    float c = 2.0f * lrbuf[b] * s_t[b];

    float4 q4 = ((const float4*)(qm + base))[tid];
    float4 x4;
    if (FIRST) {
        const float inv0 = 1.0f / (float)MM;
        x4 = make_float4(inv0, inv0, inv0, inv0);
    } else {
        x4 = ((const float4*)(Xin + base))[tid];
        float4 f4 = ((const float4*)(f + (size_t)b * MM))[tid];
        x4.x *= f4.x; x4.y *= f4.y; x4.z *= f4.z; x4.w *= f4.w;
    }

    float4 v;
    v.x = fminf(fmaxf(x4.x - c*q4.x, 0.f), 1.f);
    v.y = fminf(fmaxf(x4.y - c*q4.y, 0.f), 1.f);
    v.z = fminf(fmaxf(x4.z - c*q4.z, 0.f), 1.f);
    v.w = fminf(fmaxf(x4.w - c*q4.w, 0.f), 1.f);

    float sum = v.x + v.y + v.z + v.w;
    #pragma unroll
    for (int off = 32; off; off >>= 1) sum += __shfl_down(sum, off);

    __shared__ float red[2];
    if ((tid & 63) == 0) red[tid >> 6] = sum;
    __syncthreads();
    float rowsum = red[0] + red[1];
    float inv = 1.0f / (rowsum + 1e-8f);

    float4 o = make_float4(v.x*inv, v.y*inv, v.z*inv, v.w*inv);
    ((float4*)(Xout + base))[tid] = o;
}

// ---------------------------------------------------------------------------
// K2 (col phase): per 32-column strip of one batch:
//   colsum[i] = sum_j X2[b,j,i];  f[b,i] = min(1, 2/(colsum+1e-8))
//   colq[i]   = sum_j qm[b,j,i]*X2[b,j,i]
//   s_next[b] += sum_i f[i]*colq[i]       (lazy: never materializes scaled X)
// block (32,32): tx = column lane (coalesced), ty strides j.
// ---------------------------------------------------------------------------
__global__ __launch_bounds__(1024) void k2_col_kernel(
    const float* __restrict__ qm, const float* __restrict__ X,
    float* __restrict__ f, float* __restrict__ s_next)
{
    int b  = blockIdx.y;
    int i  = blockIdx.x * 32 + threadIdx.x;
    int ty = threadIdx.y;
    size_t bbase = (size_t)b * NN * MM;

    float cs = 0.f, cq = 0.f;
    for (int j = ty; j < NN; j += 32) {
        size_t idx = bbase + (size_t)j * MM + i;
        float x = X[idx];
        float q = qm[idx];
        cs += x;
        cq += x * q;
    }

    __shared__ float ps[32][33];
    __shared__ float pq[32][33];
    ps[ty][threadIdx.x] = cs;
    pq[ty][threadIdx.x] = cq;
    __syncthreads();

    __shared__ float sred[32];
    if (ty == 0) {
        int tx = threadIdx.x;
        float csum = 0.f, qsum = 0.f;
        #pragma unroll
        for (int k = 0; k < 32; ++k) { csum += ps[k][tx]; qsum += pq[k][tx]; }
        float fi = fminf(1.0f, 2.0f / (csum + 1e-8f));
        f[b * MM + i] = fi;
        sred[tx] = fi * qsum;
    }
    __syncthreads();
    if (ty == 0 && threadIdx.x == 0) {
        float t = 0.f;
        #pragma unroll
        for (int k = 0; k < 32; ++k) t += sred[k];
        atomicAdd(&s_next[b], t);
    }
}

// ---------------------------------------------------------------------------
// finalize: out = X2 * f  (apply the last lazy column scale)
// ---------------------------------------------------------------------------
__global__ __launch_bounds__(256) void finalize_kernel(
    const float* __restrict__ X, const float* __restrict__ f,
    float* __restrict__ out)
{
    size_t e = (size_t)blockIdx.x * blockDim.x + threadIdx.x;  // float4 index
    size_t idx = e * 4;
    int i = (int)(idx & (MM - 1));
    int b = (int)(idx >> 18);                                  // NN*MM = 2^18
    float4 x = ((const float4*)X)[e];
    float4 ff = *(const float4*)(f + (size_t)b * MM + i);
    float4 o = make_float4(x.x*ff.x, x.y*ff.y, x.z*ff.z, x.w*ff.w);
    ((float4*)out)[e] = o;
}

// ---------------------------------------------------------------------------
extern "C" void kernel_launch(void* const* d_in, const int* in_sizes, int n_in,
                              void* d_out, int out_size, void* d_ws, size_t ws_size,
                              hipStream_t stream)
{
    const float* nc = (const float*)d_in[0];  // n_emb_cur (16,512,128)
    const float* ec = (const float*)d_in[1];  // e_emb_cur
    const float* nn = (const float*)d_in[2];  // n_emb_nxt
    const float* en = (const float*)d_in[3];  // e_emb_nxt
    float* out = (float*)d_out;               // (16, 512*512) fp32

    char* ws = (char*)d_ws;
    const size_t QM_BYTES = (size_t)BATCH * NN * MM * 4;   // 16.78 MB
    float* qm    = (float*)(ws);
    float* X2    = (float*)(ws + QM_BYTES);
    float* f     = (float*)(ws + 2*QM_BYTES);                       // 32 KB
    float* rc    = (float*)(ws + 2*QM_BYTES + 32768);               // 32 KB
    float* rn    = (float*)(ws + 2*QM_BYTES + 65536);               // 32 KB
    float* sumq  = (float*)(ws + 2*QM_BYTES + 98304);               // 64 B
    float* sumq2 = (float*)(ws + 2*QM_BYTES + 98304 + 256);
    float* lrbuf = (float*)(ws + 2*QM_BYTES + 98304 + 512);
    float* sbuf  = (float*)(ws + 2*QM_BYTES + 98304 + 768);         // (QP_ITERS+2)*16 floats

    zero_scalars_kernel<<<1, 512, 0, stream>>>(sumq, sumq2, sbuf);
    row_norms_kernel<<<BATCH * 512, 64, 0, stream>>>(nc, ec, nn, en, rc, rn);
    gemm_q_kernel<<<dim3(8, 8, BATCH), 256, 0, stream>>>(nc, ec, nn, en, rc, rn,
                                                         qm, sumq, sumq2);
    init_scalars_kernel<<<1, 64, 0, stream>>>(sumq, sumq2, lrbuf, sbuf);

    // iteration 1: X0 = 1/m implicit, no column factor yet
    k1_row_kernel<true><<<BATCH * NN, 128, 0, stream>>>(qm, X2, f, lrbuf,
                                                        sbuf + 1 * BATCH, X2);
    k2_col_kernel<<<dim3(MM / 32, BATCH), dim3(32, 32), 0, stream>>>(qm, X2, f,
                                                                     sbuf + 2 * BATCH);
    for (int t = 2; t <= QP_ITERS; ++t) {
        k1_row_kernel<false><<<BATCH * NN, 128, 0, stream>>>(qm, X2, f, lrbuf,
                                                             sbuf + t * BATCH, X2);
        k2_col_kernel<<<dim3(MM / 32, BATCH), dim3(32, 32), 0, stream>>>(qm, X2, f,
                                                                         sbuf + (t + 1) * BATCH);
    }

    finalize_kernel<<<(BATCH * NN * MM / 4) / 256, 256, 0, stream>>>(X2, f, out);
}